// Round 1
// baseline (45.637 us; speedup 1.0000x reference)
//
#include <hip/hip_runtime.h>

// SeqMasking: right-align kept tokens (rand > 0.15), zero-fill left prefix.
// B=64, T=2048, D=256, fp32.
//
// ws layout: int l[B]  at offset 0
//            int src[B][T] at offset 256 bytes (B*4 = 256, already 256B aligned)

#define P_DROP 0.15f

__global__ __launch_bounds__(256)
void seqmask_scan_kernel(const float* __restrict__ rand,
                         int* __restrict__ l_out,
                         int* __restrict__ src,
                         int T) {
    const int b   = blockIdx.x;
    const int tid = threadIdx.x;
    const int EPT = T / 256;               // elements per thread (8)
    const float* r = rand + (size_t)b * T;

    int keep[8];
    int cnt = 0;
#pragma unroll
    for (int i = 0; i < 8; ++i) {
        float v = r[tid * EPT + i];
        keep[i] = (v > P_DROP) ? 1 : 0;
        cnt += keep[i];
    }

    __shared__ int s[256];
    s[tid] = cnt;
    __syncthreads();

    // Hillis-Steele inclusive scan over 256 thread-counts
#pragma unroll
    for (int off = 1; off < 256; off <<= 1) {
        int mine = s[tid];
        int add  = (tid >= off) ? s[tid - off] : 0;
        __syncthreads();
        s[tid] = mine + add;
        __syncthreads();
    }

    const int excl  = (tid == 0) ? 0 : s[tid - 1];
    const int total = s[255];
    if (tid == 0) l_out[b] = total;

    int pos = excl;
#pragma unroll
    for (int i = 0; i < 8; ++i) {
        if (keep[i]) {
            src[(size_t)b * T + pos] = tid * EPT + i;
            ++pos;
        }
    }
}

__global__ __launch_bounds__(256)
void seqmask_gather_kernel(const float* __restrict__ x,
                           const int* __restrict__ l_arr,
                           const int* __restrict__ src,
                           float* __restrict__ out,
                           int T, int D) {
    // One wave (64 lanes) per output row; 4 rows per block.
    const int row  = blockIdx.x * 4 + (threadIdx.x >> 6);
    const int lane = threadIdx.x & 63;
    const int b    = row >> 11;            // T = 2048
    const int j    = row & (T - 1);

    const int l = l_arr[b];                // wave-uniform -> scalar load
    const int q = j - (T - l);

    float4 v = make_float4(0.f, 0.f, 0.f, 0.f);
    if (q >= 0) {
        const int st = src[(size_t)b * T + q];
        v = *reinterpret_cast<const float4*>(
                x + ((size_t)b * T + st) * D + lane * 4);
    }
    *reinterpret_cast<float4*>(out + (size_t)row * D + lane * 4) = v;
}

extern "C" void kernel_launch(void* const* d_in, const int* in_sizes, int n_in,
                              void* d_out, int out_size, void* d_ws, size_t ws_size,
                              hipStream_t stream) {
    const float* x    = (const float*)d_in[0];   // (B, T, D) fp32
    const float* rand = (const float*)d_in[1];   // (B, T)    fp32
    float* out        = (float*)d_out;

    const int T  = 2048;
    const int BT = in_sizes[1];                  // B*T
    const int B  = BT / T;
    const int D  = in_sizes[0] / BT;             // 256

    int* l_arr = (int*)d_ws;
    int* src   = (int*)((char*)d_ws + 256);

    seqmask_scan_kernel<<<B, 256, 0, stream>>>(rand, l_arr, src, T);
    seqmask_gather_kernel<<<BT / 4, 256, 0, stream>>>(x, l_arr, src, out, T, D);
}